// Round 1
// baseline (506.555 us; speedup 1.0000x reference)
//
#include <hip/hip_runtime.h>
#include <math.h>

#define BB 4096        // batch size
#define DD 512         // repr dim
#define KTOP 9         // K+1
#define MARGIN_F 0.2f

// key ordering: (val desc, idx asc) — matches stable argsort of -sim
__device__ __forceinline__ bool key_gt(float va, int ia, float vb, int ib) {
  return (va > vb) || (va == vb && ia < ib);
}

// ---------------- K0: row squared norms ----------------
__global__ __launch_bounds__(64) void sqnorm_kernel(const float* __restrict__ R,
                                                    float* __restrict__ sq) {
  const int row = blockIdx.x;
  const int lane = threadIdx.x;
  const float* r = R + (size_t)row * DD;
  float4 v1 = ((const float4*)r)[lane];
  float4 v2 = ((const float4*)r)[lane + 64];
  float s = v1.x*v1.x + v1.y*v1.y + v1.z*v1.z + v1.w*v1.w
          + v2.x*v2.x + v2.y*v2.y + v2.z*v2.z + v2.w*v2.w;
  #pragma unroll
  for (int off = 32; off; off >>= 1) s += __shfl_down(s, off);
  if (lane == 0) sq[row] = s;
}

// ---------------- K1: fp32 tiled GEMM + sim_hat epilogue ----------------
#define BT 64
#define BK 32
__global__ __launch_bounds__(256) void simgemm(const float* __restrict__ R,
                                               const int* __restrict__ labels,
                                               const float* __restrict__ sq,
                                               float* __restrict__ sim) {
  __shared__ float As[BK][BT + 4];   // transposed: As[k][row], pad 4 floats
  __shared__ float Bs[BK][BT + 4];
  const int i0 = blockIdx.y * BT;
  const int j0 = blockIdx.x * BT;
  const int tid = threadIdx.x;
  const int tx = tid & 15, ty = tid >> 4;
  const int lr = tid >> 3;           // 0..31
  const int lc = (tid & 7) << 2;     // 0,4,...,28

  float acc[4][4] = {};

  for (int k0 = 0; k0 < DD; k0 += BK) {
    const float4 a0 = *(const float4*)&R[(size_t)(i0 + lr)      * DD + k0 + lc];
    const float4 a1 = *(const float4*)&R[(size_t)(i0 + lr + 32) * DD + k0 + lc];
    const float4 b0 = *(const float4*)&R[(size_t)(j0 + lr)      * DD + k0 + lc];
    const float4 b1 = *(const float4*)&R[(size_t)(j0 + lr + 32) * DD + k0 + lc];
    __syncthreads();   // previous iteration's reads done before overwrite
    As[lc+0][lr] = a0.x; As[lc+1][lr] = a0.y; As[lc+2][lr] = a0.z; As[lc+3][lr] = a0.w;
    As[lc+0][lr+32] = a1.x; As[lc+1][lr+32] = a1.y; As[lc+2][lr+32] = a1.z; As[lc+3][lr+32] = a1.w;
    Bs[lc+0][lr] = b0.x; Bs[lc+1][lr] = b0.y; Bs[lc+2][lr] = b0.z; Bs[lc+3][lr] = b0.w;
    Bs[lc+0][lr+32] = b1.x; Bs[lc+1][lr+32] = b1.y; Bs[lc+2][lr+32] = b1.z; Bs[lc+3][lr+32] = b1.w;
    __syncthreads();
    #pragma unroll 8
    for (int kk = 0; kk < BK; ++kk) {
      const float4 av = *(const float4*)&As[kk][ty * 4];
      const float4 bv = *(const float4*)&Bs[kk][tx * 4];
      acc[0][0] += av.x*bv.x; acc[0][1] += av.x*bv.y; acc[0][2] += av.x*bv.z; acc[0][3] += av.x*bv.w;
      acc[1][0] += av.y*bv.x; acc[1][1] += av.y*bv.y; acc[1][2] += av.y*bv.z; acc[1][3] += av.y*bv.w;
      acc[2][0] += av.z*bv.x; acc[2][1] += av.z*bv.y; acc[2][2] += av.z*bv.z; acc[2][3] += av.z*bv.w;
      acc[3][0] += av.w*bv.x; acc[3][1] += av.w*bv.y; acc[3][2] += av.w*bv.z; acc[3][3] += av.w*bv.w;
    }
  }

  // epilogue: res = sq_i - 2*dot + sq_j; d = res<=0 ? 0 : sqrt(res); sim = -d + (diff?margin:0)
  const int orow = i0 + ty * 4;
  const int ocol = j0 + tx * 4;
  float sqc[4]; int labc[4];
  #pragma unroll
  for (int n = 0; n < 4; ++n) { sqc[n] = sq[ocol + n]; labc[n] = labels[ocol + n]; }
  #pragma unroll
  for (int m = 0; m < 4; ++m) {
    const float sr = sq[orow + m];
    const int lm = labels[orow + m];
    float4 o;
    {
      float res = sr - 2.f * acc[m][0] + sqc[0];
      float dd = (res <= 0.f) ? 0.f : sqrtf(res);
      o.x = -dd + ((lm != labc[0]) ? MARGIN_F : 0.f);
    }
    {
      float res = sr - 2.f * acc[m][1] + sqc[1];
      float dd = (res <= 0.f) ? 0.f : sqrtf(res);
      o.y = -dd + ((lm != labc[1]) ? MARGIN_F : 0.f);
    }
    {
      float res = sr - 2.f * acc[m][2] + sqc[2];
      float dd = (res <= 0.f) ? 0.f : sqrtf(res);
      o.z = -dd + ((lm != labc[2]) ? MARGIN_F : 0.f);
    }
    {
      float res = sr - 2.f * acc[m][3] + sqc[3];
      float dd = (res <= 0.f) ? 0.f : sqrtf(res);
      o.w = -dd + ((lm != labc[3]) ? MARGIN_F : 0.f);
    }
    *(float4*)&sim[(size_t)(orow + m) * BB + ocol] = o;
  }
}

// ---------------- K2: per-row rank processing ----------------
__global__ __launch_bounds__(256) void rowproc(const float* __restrict__ sim,
                                               const int* __restrict__ labels,
                                               float* __restrict__ partials) {
  constexpr int T = 256;
  __shared__ float srow[BB];
  __shared__ int   slab[BB];
  __shared__ float sv[T];
  __shared__ int   si[T];
  __shared__ int   scnt[T];
  __shared__ float top_v[KTOP];
  __shared__ int   top_i[KTOP];

  const int row = blockIdx.x;
  const int tid = threadIdx.x;
  const float* srcp = sim + (size_t)row * BB;

  for (int j = tid; j < BB / 4; j += T) {
    ((float4*)srow)[j] = ((const float4*)srcp)[j];
    ((int4*)slab)[j]   = ((const int4*)labels)[j];
  }
  __syncthreads();

  const int mylab = slab[row];

  // pos_num = count of same-class (incl self)
  int c = 0;
  for (int j = tid; j < BB; j += T) c += (slab[j] == mylab) ? 1 : 0;
  scnt[tid] = c; __syncthreads();
  #pragma unroll
  for (int s = 128; s; s >>= 1) { if (tid < s) scnt[tid] += scnt[tid + s]; __syncthreads(); }
  const int ks = min(scnt[0], KTOP);
  __syncthreads();

  // iterative tie-ordered top-ks selection
  float pv = INFINITY; int pi = -1;
  for (int t = 0; t < ks; ++t) {
    float bv = -INFINITY; int bi_ = BB;
    for (int j = tid; j < BB; j += T) {
      const float v = srow[j];
      if (key_gt(pv, pi, v, j) && key_gt(v, j, bv, bi_)) { bv = v; bi_ = j; }
    }
    sv[tid] = bv; si[tid] = bi_; __syncthreads();
    #pragma unroll
    for (int s = 128; s; s >>= 1) {
      if (tid < s && key_gt(sv[tid + s], si[tid + s], sv[tid], si[tid])) {
        sv[tid] = sv[tid + s]; si[tid] = si[tid + s];
      }
      __syncthreads();
    }
    pv = sv[0]; pi = si[0];
    if (tid == 0) { top_v[t] = pv; top_i[t] = pi; }
    __syncthreads();
  }

  // fp term: different-class entries within top-ks; rank = t+1
  float fp = 0.f; int fp_num = 0;
  for (int t = 0; t < ks; ++t) {
    if (slab[top_i[t]] != mylab) {
      fp += top_v[t] * (1.f / log2f((float)(t + 2)) + 1.f);
      fp_num++;
    }
  }

  // fn term: top fp_num same-class entries strictly below the ks-th key,
  // weighted by their TRUE global rank
  float fn = 0.f;
  float pv2 = top_v[ks - 1]; int pi2 = top_i[ks - 1];
  for (int u = 0; u < fp_num; ++u) {
    float bv = -INFINITY; int bi_ = BB;
    for (int j = tid; j < BB; j += T) {
      if (slab[j] != mylab) continue;
      const float v = srow[j];
      if (key_gt(pv2, pi2, v, j) && key_gt(v, j, bv, bi_)) { bv = v; bi_ = j; }
    }
    sv[tid] = bv; si[tid] = bi_; __syncthreads();
    #pragma unroll
    for (int s = 128; s; s >>= 1) {
      if (tid < s && key_gt(sv[tid + s], si[tid + s], sv[tid], si[tid])) {
        sv[tid] = sv[tid + s]; si[tid] = si[tid + s];
      }
      __syncthreads();
    }
    const float fv = sv[0]; const int fi = si[0];
    __syncthreads();
    if (fi >= BB) break;  // uniform across block: no candidates left

    // global rank of (fv, fi)
    int cc = 0;
    for (int j = tid; j < BB; j += T) {
      if (key_gt(srow[j], j, fv, fi)) cc++;
    }
    scnt[tid] = cc; __syncthreads();
    #pragma unroll
    for (int s = 128; s; s >>= 1) { if (tid < s) scnt[tid] += scnt[tid + s]; __syncthreads(); }
    const int rank = scnt[0] + 1;
    __syncthreads();

    fn += fv * (1.f / log2f((float)(rank + 1)) + 1.f);
    pv2 = fv; pi2 = fi;
  }

  if (tid == 0) partials[row] = fp - fn;
}

// ---------------- K3: deterministic final reduction ----------------
__global__ __launch_bounds__(256) void finalreduce(const float* __restrict__ partials,
                                                   float* __restrict__ out) {
  __shared__ float s[256];
  const int tid = threadIdx.x;
  float acc = 0.f;
  for (int j = tid; j < BB; j += 256) acc += partials[j];
  s[tid] = acc; __syncthreads();
  #pragma unroll
  for (int st = 128; st; st >>= 1) { if (tid < st) s[tid] += s[tid + st]; __syncthreads(); }
  if (tid == 0) out[0] = s[0];
}

extern "C" void kernel_launch(void* const* d_in, const int* in_sizes, int n_in,
                              void* d_out, int out_size, void* d_ws, size_t ws_size,
                              hipStream_t stream) {
  const float* R      = (const float*)d_in[0];
  const int*   labels = (const int*)d_in[1];
  float* out = (float*)d_out;

  float* sim      = (float*)d_ws;                                   // 4096*4096*4 = 64 MB
  float* sq       = (float*)((char*)d_ws + (size_t)BB * BB * 4);    // 16 KB
  float* partials = sq + BB;                                        // 16 KB

  sqnorm_kernel<<<BB, 64, 0, stream>>>(R, sq);
  dim3 g(BB / BT, BB / BT);
  simgemm<<<g, 256, 0, stream>>>(R, labels, sq, sim);
  rowproc<<<BB, 256, 0, stream>>>(sim, labels, partials);
  finalreduce<<<1, 256, 0, stream>>>(partials, out);
}

// Round 2
// 350.383 us; speedup vs baseline: 1.4457x; 1.4457x over previous
//
#include <hip/hip_runtime.h>
#include <math.h>

#define BB 4096        // batch size
#define DD 512         // repr dim
#define KTOP 9         // K+1
#define MARGIN_F 0.2f
#define T 256          // rowproc block size

// ---- sortable key: (sim desc, idx asc)  ->  u64 max-order ----
__device__ __forceinline__ unsigned long long mkkey(float v, int j) {
  unsigned s = __float_as_uint(v);
  unsigned ord = s ^ ((unsigned)((int)s >> 31) | 0x80000000u);  // monotone float->uint
  return ((unsigned long long)ord << 32) | (unsigned)(BB - 1 - j);
}

__device__ __forceinline__ unsigned long long shflxor64(unsigned long long v, int m) {
  unsigned lo = (unsigned)v, hi = (unsigned)(v >> 32);
  lo = (unsigned)__shfl_xor((int)lo, m);
  hi = (unsigned)__shfl_xor((int)hi, m);
  return ((unsigned long long)hi << 32) | lo;
}

// ---------------- K0: row squared norms ----------------
__global__ __launch_bounds__(64) void sqnorm_kernel(const float* __restrict__ R,
                                                    float* __restrict__ sq) {
  const int row = blockIdx.x;
  const int lane = threadIdx.x;
  const float* r = R + (size_t)row * DD;
  float4 v1 = ((const float4*)r)[lane];
  float4 v2 = ((const float4*)r)[lane + 64];
  float s = v1.x*v1.x + v1.y*v1.y + v1.z*v1.z + v1.w*v1.w
          + v2.x*v2.x + v2.y*v2.y + v2.z*v2.z + v2.w*v2.w;
  #pragma unroll
  for (int off = 32; off; off >>= 1) s += __shfl_down(s, off);
  if (lane == 0) sq[row] = s;
}

// ---------------- K0b: pack labels to bytes ----------------
__global__ __launch_bounds__(256) void packlab(const int* __restrict__ labels,
                                               unsigned char* __restrict__ lab8) {
  int j = blockIdx.x * 256 + threadIdx.x;
  lab8[j] = (unsigned char)labels[j];
}

// ---------------- K1: fp32 tiled GEMM + sim_hat epilogue ----------------
#define BT 64
#define BK 32
__global__ __launch_bounds__(256) void simgemm(const float* __restrict__ R,
                                               const int* __restrict__ labels,
                                               const float* __restrict__ sq,
                                               float* __restrict__ sim) {
  __shared__ float As[BK][BT + 4];   // transposed: As[k][row], pad 4 floats
  __shared__ float Bs[BK][BT + 4];
  const int i0 = blockIdx.y * BT;
  const int j0 = blockIdx.x * BT;
  const int tid = threadIdx.x;
  const int tx = tid & 15, ty = tid >> 4;
  const int lr = tid >> 3;           // 0..31
  const int lc = (tid & 7) << 2;     // 0,4,...,28

  float acc[4][4] = {};

  for (int k0 = 0; k0 < DD; k0 += BK) {
    const float4 a0 = *(const float4*)&R[(size_t)(i0 + lr)      * DD + k0 + lc];
    const float4 a1 = *(const float4*)&R[(size_t)(i0 + lr + 32) * DD + k0 + lc];
    const float4 b0 = *(const float4*)&R[(size_t)(j0 + lr)      * DD + k0 + lc];
    const float4 b1 = *(const float4*)&R[(size_t)(j0 + lr + 32) * DD + k0 + lc];
    __syncthreads();
    As[lc+0][lr] = a0.x; As[lc+1][lr] = a0.y; As[lc+2][lr] = a0.z; As[lc+3][lr] = a0.w;
    As[lc+0][lr+32] = a1.x; As[lc+1][lr+32] = a1.y; As[lc+2][lr+32] = a1.z; As[lc+3][lr+32] = a1.w;
    Bs[lc+0][lr] = b0.x; Bs[lc+1][lr] = b0.y; Bs[lc+2][lr] = b0.z; Bs[lc+3][lr] = b0.w;
    Bs[lc+0][lr+32] = b1.x; Bs[lc+1][lr+32] = b1.y; Bs[lc+2][lr+32] = b1.z; Bs[lc+3][lr+32] = b1.w;
    __syncthreads();
    #pragma unroll 8
    for (int kk = 0; kk < BK; ++kk) {
      const float4 av = *(const float4*)&As[kk][ty * 4];
      const float4 bv = *(const float4*)&Bs[kk][tx * 4];
      acc[0][0] += av.x*bv.x; acc[0][1] += av.x*bv.y; acc[0][2] += av.x*bv.z; acc[0][3] += av.x*bv.w;
      acc[1][0] += av.y*bv.x; acc[1][1] += av.y*bv.y; acc[1][2] += av.y*bv.z; acc[1][3] += av.y*bv.w;
      acc[2][0] += av.z*bv.x; acc[2][1] += av.z*bv.y; acc[2][2] += av.z*bv.z; acc[2][3] += av.z*bv.w;
      acc[3][0] += av.w*bv.x; acc[3][1] += av.w*bv.y; acc[3][2] += av.w*bv.z; acc[3][3] += av.w*bv.w;
    }
  }

  const int orow = i0 + ty * 4;
  const int ocol = j0 + tx * 4;
  float sqc[4]; int labc[4];
  #pragma unroll
  for (int n = 0; n < 4; ++n) { sqc[n] = sq[ocol + n]; labc[n] = labels[ocol + n]; }
  #pragma unroll
  for (int m = 0; m < 4; ++m) {
    const float sr = sq[orow + m];
    const int lm = labels[orow + m];
    float o[4];
    #pragma unroll
    for (int n = 0; n < 4; ++n) {
      float res = sr - 2.f * acc[m][n] + sqc[n];
      float dd = (res <= 0.f) ? 0.f : sqrtf(res);
      o[n] = -dd + ((lm != labc[n]) ? MARGIN_F : 0.f);
    }
    *(float4*)&sim[(size_t)(orow + m) * BB + ocol] = make_float4(o[0], o[1], o[2], o[3]);
  }
}

// ---------------- K2: per-row rank processing (pop-based) ----------------
__global__ __launch_bounds__(256) void rowproc2(const float* __restrict__ sim,
                                                const int* __restrict__ labels,
                                                const unsigned char* __restrict__ lab8,
                                                float* __restrict__ partials) {
  __shared__ float4 srow4[BB / 4];
  __shared__ unsigned slabw[BB / 4];
  __shared__ unsigned long long wred[4];
  __shared__ unsigned long long gshared;
  __shared__ unsigned long long stop9[KTOP];
  __shared__ unsigned long long candk[KTOP];
  __shared__ int wcnt[4][KTOP];
  __shared__ int ipar[4];
  __shared__ int sks, sfpnum;
  __shared__ float sfp;
  __shared__ unsigned long long skth;

  float* srow = (float*)srow4;
  unsigned char* slab = (unsigned char*)slabw;

  const int tid = threadIdx.x;
  const int row = blockIdx.x;
  const int wid = tid >> 6, lane = tid & 63;

  // ---- stage row + labels ----
  const float4* srcp = (const float4*)(sim + (size_t)row * BB);
  const unsigned* lsrc = (const unsigned*)lab8;
  #pragma unroll
  for (int s = 0; s < 4; ++s) {
    int j4 = tid + s * T;
    srow4[j4] = srcp[j4];
    slabw[j4] = lsrc[j4];
  }
  __syncthreads();

  const int mylab = slab[row];

  // ---- pos count + initial head ----
  int c = 0;
  unsigned long long head = 0;
  #pragma unroll
  for (int s = 0; s < 16; ++s) {
    int j = tid + s * T;
    float v = srow[j];
    c += (slab[j] == mylab) ? 1 : 0;
    unsigned long long k = mkkey(v, j);
    if (k > head) head = k;
  }
  #pragma unroll
  for (int off = 32; off; off >>= 1) c += __shfl_xor(c, off);
  if (lane == 0) ipar[wid] = c;
  __syncthreads();
  if (tid == 0) sks = min(ipar[0] + ipar[1] + ipar[2] + ipar[3], KTOP);
  __syncthreads();
  const int ks = sks;

  // ---- top-ks pops (global argmax; unique winner rescans its 16 elems) ----
  for (int t = 0; t < ks; ++t) {
    unsigned long long h = head;
    #pragma unroll
    for (int off = 32; off; off >>= 1) {
      unsigned long long o = shflxor64(h, off);
      if (o > h) h = o;
    }
    if (lane == 0) wred[wid] = h;
    __syncthreads();
    if (tid == 0) {
      unsigned long long m = wred[0];
      #pragma unroll
      for (int w = 1; w < 4; ++w) if (wred[w] > m) m = wred[w];
      gshared = m; stop9[t] = m;
    }
    __syncthreads();
    const unsigned long long g = gshared;
    if (head == g) {   // exactly one thread (keys unique)
      unsigned long long nb = 0;
      #pragma unroll
      for (int s = 0; s < 16; ++s) {
        int j = tid + s * T;
        unsigned long long k = mkkey(srow[j], j);
        if (k < g && k > nb) nb = k;
      }
      head = nb;
    }
  }

  // ---- fp term (thread 0; ks <= 9 entries) ----
  if (tid == 0) {
    float fp = 0.f; int fpn = 0;
    for (int t = 0; t < ks; ++t) {
      int j = BB - 1 - (int)(unsigned)(stop9[t] & 0xFFFFFFFFull);
      if (slab[j] != mylab) {
        fp += srow[j] * (1.f / log2f((float)(t + 2)) + 1.f);
        fpn++;
      }
    }
    sfp = fp; sfpnum = fpn; skth = stop9[ks - 1];
  }
  __syncthreads();
  const int fpnum = sfpnum;
  const unsigned long long kth = skth;

  int nc = 0;
  if (fpnum > 0) {
    // ---- fn candidate heads: same-class, key strictly below kth ----
    unsigned long long h2 = 0;
    #pragma unroll
    for (int s = 0; s < 16; ++s) {
      int j = tid + s * T;
      if (slab[j] != mylab) continue;
      unsigned long long k = mkkey(srow[j], j);
      if (k < kth && k > h2) h2 = k;
    }
    for (int u = 0; u < fpnum; ++u) {
      unsigned long long h = h2;
      #pragma unroll
      for (int off = 32; off; off >>= 1) {
        unsigned long long o = shflxor64(h, off);
        if (o > h) h = o;
      }
      if (lane == 0) wred[wid] = h;
      __syncthreads();
      if (tid == 0) {
        unsigned long long m = wred[0];
        #pragma unroll
        for (int w = 1; w < 4; ++w) if (wred[w] > m) m = wred[w];
        gshared = m;
      }
      __syncthreads();
      const unsigned long long g = gshared;
      if (g == 0) break;          // uniform: no candidates left
      if (tid == 0) candk[u] = g;
      ++nc;
      if (h2 == g) {
        unsigned long long nb = 0;
        #pragma unroll
        for (int s = 0; s < 16; ++s) {
          int j = tid + s * T;
          if (slab[j] != mylab) continue;
          unsigned long long k = mkkey(srow[j], j);
          if (k < g && k > nb) nb = k;
        }
        h2 = nb;
      }
    }
    __syncthreads();   // publish candk to all threads (nc uniform)
  }

  if (fpnum > 0 && nc > 0) {
    // ---- one counting pass: global rank of every candidate ----
    unsigned long long ck[KTOP];
    int cnt[KTOP];
    #pragma unroll
    for (int q = 0; q < KTOP; ++q) {
      ck[q] = (q < nc) ? candk[q] : ~0ull;
      cnt[q] = 0;
    }
    #pragma unroll
    for (int s = 0; s < 16; ++s) {
      int j = tid + s * T;
      unsigned long long k = mkkey(srow[j], j);
      #pragma unroll
      for (int q = 0; q < KTOP; ++q) cnt[q] += (k > ck[q]) ? 1 : 0;
    }
    #pragma unroll
    for (int q = 0; q < KTOP; ++q) {
      int x = cnt[q];
      #pragma unroll
      for (int off = 32; off; off >>= 1) x += __shfl_xor(x, off);
      if (lane == 0) wcnt[wid][q] = x;
    }
    __syncthreads();
    if (tid == 0) {
      float fn = 0.f;
      for (int u = 0; u < nc; ++u) {
        int rank = 1 + wcnt[0][u] + wcnt[1][u] + wcnt[2][u] + wcnt[3][u];
        int j = BB - 1 - (int)(unsigned)(candk[u] & 0xFFFFFFFFull);
        fn += srow[j] * (1.f / log2f((float)(rank + 1)) + 1.f);
      }
      partials[row] = sfp - fn;
    }
  } else if (tid == 0) {
    partials[row] = sfp;
  }
}

// ---------------- K3: deterministic final reduction ----------------
__global__ __launch_bounds__(256) void finalreduce(const float* __restrict__ partials,
                                                   float* __restrict__ out) {
  __shared__ float s[256];
  const int tid = threadIdx.x;
  float acc = 0.f;
  for (int j = tid; j < BB; j += 256) acc += partials[j];
  s[tid] = acc; __syncthreads();
  #pragma unroll
  for (int st = 128; st; st >>= 1) { if (tid < st) s[tid] += s[tid + st]; __syncthreads(); }
  if (tid == 0) out[0] = s[0];
}

extern "C" void kernel_launch(void* const* d_in, const int* in_sizes, int n_in,
                              void* d_out, int out_size, void* d_ws, size_t ws_size,
                              hipStream_t stream) {
  const float* R      = (const float*)d_in[0];
  const int*   labels = (const int*)d_in[1];
  float* out = (float*)d_out;

  float* sim            = (float*)d_ws;                                  // 64 MB
  float* sq             = (float*)((char*)d_ws + (size_t)BB * BB * 4);   // 16 KB
  float* partials       = sq + BB;                                       // 16 KB
  unsigned char* lab8   = (unsigned char*)(partials + BB);               // 4 KB

  sqnorm_kernel<<<BB, 64, 0, stream>>>(R, sq);
  packlab<<<BB / 256, 256, 0, stream>>>(labels, lab8);
  dim3 g(BB / BT, BB / BT);
  simgemm<<<g, 256, 0, stream>>>(R, labels, sq, sim);
  rowproc2<<<BB, 256, 0, stream>>>(sim, labels, lab8, partials);
  finalreduce<<<1, 256, 0, stream>>>(partials, out);
}

// Round 3
// 190.462 us; speedup vs baseline: 2.6596x; 1.8396x over previous
//
#include <hip/hip_runtime.h>
#include <math.h>

#define BB 4096        // batch size
#define DD 512         // repr dim
#define KTOP 9         // K+1
#define MARGIN_F 0.2f
#define T 256          // rowproc block size

typedef __attribute__((ext_vector_type(8))) short short8;
typedef __attribute__((ext_vector_type(4))) float f32x4;

// split-fp32 operands (4 MB each), module-scope device memory (no ws needed)
__device__ unsigned short g_Rhi[(size_t)BB * DD];
__device__ unsigned short g_Rlo[(size_t)BB * DD];

// ---- bf16 helpers (RNE) ----
__device__ __forceinline__ unsigned short f2bf(float x) {
  unsigned u = __float_as_uint(x);
  u += 0x7fffu + ((u >> 16) & 1u);
  return (unsigned short)(u >> 16);
}
__device__ __forceinline__ float bf2f(unsigned short h) {
  return __uint_as_float((unsigned)h << 16);
}

// async global->LDS, 16B per lane; LDS dest = wave-uniform base + lane*16
__device__ __forceinline__ void gload16(void* lds, const void* g) {
  __builtin_amdgcn_global_load_lds(
      (const __attribute__((address_space(1))) void*)g,
      (__attribute__((address_space(3))) void*)lds, 16, 0, 0);
}

// ---- sortable key: (sim desc, idx asc)  ->  u64 max-order ----
__device__ __forceinline__ unsigned long long mkkey(float v, int j) {
  unsigned s = __float_as_uint(v);
  unsigned ord = s ^ ((unsigned)((int)s >> 31) | 0x80000000u);
  return ((unsigned long long)ord << 32) | (unsigned)(BB - 1 - j);
}

__device__ __forceinline__ unsigned long long shflxor64(unsigned long long v, int m) {
  unsigned lo = (unsigned)v, hi = (unsigned)(v >> 32);
  lo = (unsigned)__shfl_xor((int)lo, m);
  hi = (unsigned)__shfl_xor((int)hi, m);
  return ((unsigned long long)hi << 32) | lo;
}

// ---------------- K0: split R into bf16 hi/lo ----------------
__global__ __launch_bounds__(256) void splitbf(const float* __restrict__ R) {
  const int i = (blockIdx.x * 256 + threadIdx.x) * 4;
  float4 v = *(const float4*)&R[i];
  float x[4] = {v.x, v.y, v.z, v.w};
  ushort4 h, l;
  unsigned short* hp = (unsigned short*)&h;
  unsigned short* lp = (unsigned short*)&l;
  #pragma unroll
  for (int q = 0; q < 4; ++q) {
    unsigned short hh = f2bf(x[q]);
    hp[q] = hh;
    lp[q] = f2bf(x[q] - bf2f(hh));
  }
  *(ushort4*)&g_Rhi[i] = h;
  *(ushort4*)&g_Rlo[i] = l;
}

// ---------------- K0b: row squared norms (fp32, exact) ----------------
__global__ __launch_bounds__(64) void sqnorm_kernel(const float* __restrict__ R,
                                                    float* __restrict__ sq) {
  const int row = blockIdx.x;
  const int lane = threadIdx.x;
  const float* r = R + (size_t)row * DD;
  float4 v1 = ((const float4*)r)[lane];
  float4 v2 = ((const float4*)r)[lane + 64];
  float s = v1.x*v1.x + v1.y*v1.y + v1.z*v1.z + v1.w*v1.w
          + v2.x*v2.x + v2.y*v2.y + v2.z*v2.z + v2.w*v2.w;
  #pragma unroll
  for (int off = 32; off; off >>= 1) s += __shfl_down(s, off);
  if (lane == 0) sq[row] = s;
}

// ---------------- K0c: pack labels to bytes ----------------
__global__ __launch_bounds__(256) void packlab(const int* __restrict__ labels,
                                               unsigned char* __restrict__ lab8) {
  int j = blockIdx.x * 256 + threadIdx.x;
  lab8[j] = (unsigned char)labels[j];
}

// ---------------- K1: MFMA split-bf16 GEMM + sim epilogue (symmetric) ----------------
// 128x128 tile, BK=32, 4 waves (2x2), each wave 64x64 via 4x4 frags of 16x16x32.
// Only bi<=bj blocks run; off-diagonal blocks also store the transposed tile.
__global__ __launch_bounds__(256) void simgemm_mfma(const int* __restrict__ labels,
                                                    const float* __restrict__ sq,
                                                    float* __restrict__ sim) {
  const int bi = blockIdx.y, bj = blockIdx.x;
  if (bi > bj) return;
  const int i0 = bi * 128, j0 = bj * 128;

  __shared__ unsigned short smem[4 * 4096];   // Ahi | Alo | Bhi | Blo, each [128][32]
  unsigned short* sAhi = smem;
  unsigned short* sAlo = smem + 4096;
  unsigned short* sBhi = smem + 8192;
  unsigned short* sBlo = smem + 12288;

  const int tid = threadIdx.x;
  const int wid = tid >> 6, lane = tid & 63;
  const int wr = wid >> 1, wc = wid & 1;
  const int lrow = lane & 15, kblk = lane >> 4;

  f32x4 acc[4][4] = {};

  const int ch0 = wid * 2;
  const int r_a = (lane >> 2);           // + chunk*16
  const int c_a = (lane & 3) * 8;

  for (int k0 = 0; k0 < DD; k0 += 32) {
    // stage 4 tiles (8 gload16 per wave)
    #pragma unroll
    for (int i = 0; i < 2; ++i) {
      const int chunk = ch0 + i;
      const int r = chunk * 16 + r_a;
      const size_t ga = (size_t)(i0 + r) * DD + k0 + c_a;
      const size_t gb = (size_t)(j0 + r) * DD + k0 + c_a;
      gload16(&sAhi[chunk * 512], &g_Rhi[ga]);
      gload16(&sAlo[chunk * 512], &g_Rlo[ga]);
      gload16(&sBhi[chunk * 512], &g_Rhi[gb]);
      gload16(&sBlo[chunk * 512], &g_Rlo[gb]);
    }
    __syncthreads();   // vmcnt(0) drain per wave + barrier -> tiles ready

    short8 ah[4], al[4], bh[4], bl[4];
    #pragma unroll
    for (int m = 0; m < 4; ++m) {
      const int off = (wr * 64 + m * 16 + lrow) * 32 + kblk * 8;
      ah[m] = *(const short8*)&sAhi[off];
      al[m] = *(const short8*)&sAlo[off];
    }
    #pragma unroll
    for (int n = 0; n < 4; ++n) {
      const int off = (wc * 64 + n * 16 + lrow) * 32 + kblk * 8;
      bh[n] = *(const short8*)&sBhi[off];
      bl[n] = *(const short8*)&sBlo[off];
    }
    #pragma unroll
    for (int m = 0; m < 4; ++m) {
      #pragma unroll
      for (int n = 0; n < 4; ++n) {
        acc[m][n] = __builtin_amdgcn_mfma_f32_16x16x32_bf16(ah[m], bh[n], acc[m][n], 0, 0, 0);
        acc[m][n] = __builtin_amdgcn_mfma_f32_16x16x32_bf16(ah[m], bl[n], acc[m][n], 0, 0, 0);
        acc[m][n] = __builtin_amdgcn_mfma_f32_16x16x32_bf16(al[m], bh[n], acc[m][n], 0, 0, 0);
      }
    }
    __syncthreads();   // all waves done reading before next-stage overwrite
  }

  // ---- epilogue: stage sq/labels slices in LDS ----
  float* sqi = (float*)smem;          // 128 floats
  float* sqj = sqi + 128;
  int* labi = (int*)(sqj + 128);
  int* labj = labi + 128;
  if (tid < 128) { sqi[tid] = sq[i0 + tid]; labi[tid] = labels[i0 + tid]; }
  else { int t = tid - 128; sqj[t] = sq[j0 + t]; labj[t] = labels[j0 + t]; }
  __syncthreads();

  const bool offdiag = (bi != bj);
  #pragma unroll
  for (int m = 0; m < 4; ++m) {
    const int rbase = wr * 64 + m * 16 + kblk * 4;   // in-tile row of reg 0
    #pragma unroll
    for (int n = 0; n < 4; ++n) {
      const int ccol = wc * 64 + n * 16 + lrow;
      const float sqc = sqj[ccol];
      const int lc_ = labj[ccol];
      float4 vals;
      float* vp = (float*)&vals;
      #pragma unroll
      for (int reg = 0; reg < 4; ++reg) {
        const int r = rbase + reg;
        float res = sqi[r] - 2.0f * acc[m][n][reg] + sqc;
        float dd = (res <= 0.f) ? 0.f : sqrtf(res);
        float sv = -dd + ((labi[r] != lc_) ? MARGIN_F : 0.f);
        vp[reg] = sv;
        sim[(size_t)(i0 + r) * BB + (j0 + ccol)] = sv;
      }
      if (offdiag) {
        *(float4*)&sim[(size_t)(j0 + ccol) * BB + (i0 + rbase)] = vals;
      }
    }
  }
}

// ---------------- K2: per-row rank processing (pop-based) ----------------
__global__ __launch_bounds__(256) void rowproc2(const float* __restrict__ sim,
                                                const int* __restrict__ labels,
                                                const unsigned char* __restrict__ lab8,
                                                float* __restrict__ partials) {
  __shared__ float4 srow4[BB / 4];
  __shared__ unsigned slabw[BB / 4];
  __shared__ unsigned long long wred[4];
  __shared__ unsigned long long gshared;
  __shared__ unsigned long long stop9[KTOP];
  __shared__ unsigned long long candk[KTOP];
  __shared__ int wcnt[4][KTOP];
  __shared__ int ipar[4];
  __shared__ int sks, sfpnum;
  __shared__ float sfp;
  __shared__ unsigned long long skth;

  float* srow = (float*)srow4;
  unsigned char* slab = (unsigned char*)slabw;

  const int tid = threadIdx.x;
  const int row = blockIdx.x;
  const int wid = tid >> 6, lane = tid & 63;

  const float4* srcp = (const float4*)(sim + (size_t)row * BB);
  const unsigned* lsrc = (const unsigned*)lab8;
  #pragma unroll
  for (int s = 0; s < 4; ++s) {
    int j4 = tid + s * T;
    srow4[j4] = srcp[j4];
    slabw[j4] = lsrc[j4];
  }
  __syncthreads();

  const int mylab = slab[row];

  int c = 0;
  unsigned long long head = 0;
  #pragma unroll
  for (int s = 0; s < 16; ++s) {
    int j = tid + s * T;
    float v = srow[j];
    c += (slab[j] == mylab) ? 1 : 0;
    unsigned long long k = mkkey(v, j);
    if (k > head) head = k;
  }
  #pragma unroll
  for (int off = 32; off; off >>= 1) c += __shfl_xor(c, off);
  if (lane == 0) ipar[wid] = c;
  __syncthreads();
  if (tid == 0) sks = min(ipar[0] + ipar[1] + ipar[2] + ipar[3], KTOP);
  __syncthreads();
  const int ks = sks;

  for (int t = 0; t < ks; ++t) {
    unsigned long long h = head;
    #pragma unroll
    for (int off = 32; off; off >>= 1) {
      unsigned long long o = shflxor64(h, off);
      if (o > h) h = o;
    }
    if (lane == 0) wred[wid] = h;
    __syncthreads();
    if (tid == 0) {
      unsigned long long m = wred[0];
      #pragma unroll
      for (int w = 1; w < 4; ++w) if (wred[w] > m) m = wred[w];
      gshared = m; stop9[t] = m;
    }
    __syncthreads();
    const unsigned long long g = gshared;
    if (head == g) {
      unsigned long long nb = 0;
      #pragma unroll
      for (int s = 0; s < 16; ++s) {
        int j = tid + s * T;
        unsigned long long k = mkkey(srow[j], j);
        if (k < g && k > nb) nb = k;
      }
      head = nb;
    }
  }

  if (tid == 0) {
    float fp = 0.f; int fpn = 0;
    for (int t = 0; t < ks; ++t) {
      int j = BB - 1 - (int)(unsigned)(stop9[t] & 0xFFFFFFFFull);
      if (slab[j] != mylab) {
        fp += srow[j] * (1.f / log2f((float)(t + 2)) + 1.f);
        fpn++;
      }
    }
    sfp = fp; sfpnum = fpn; skth = stop9[ks - 1];
  }
  __syncthreads();
  const int fpnum = sfpnum;
  const unsigned long long kth = skth;

  int nc = 0;
  if (fpnum > 0) {
    unsigned long long h2 = 0;
    #pragma unroll
    for (int s = 0; s < 16; ++s) {
      int j = tid + s * T;
      if (slab[j] != mylab) continue;
      unsigned long long k = mkkey(srow[j], j);
      if (k < kth && k > h2) h2 = k;
    }
    for (int u = 0; u < fpnum; ++u) {
      unsigned long long h = h2;
      #pragma unroll
      for (int off = 32; off; off >>= 1) {
        unsigned long long o = shflxor64(h, off);
        if (o > h) h = o;
      }
      if (lane == 0) wred[wid] = h;
      __syncthreads();
      if (tid == 0) {
        unsigned long long m = wred[0];
        #pragma unroll
        for (int w = 1; w < 4; ++w) if (wred[w] > m) m = wred[w];
        gshared = m;
      }
      __syncthreads();
      const unsigned long long g = gshared;
      if (g == 0) break;
      if (tid == 0) candk[u] = g;
      ++nc;
      if (h2 == g) {
        unsigned long long nb = 0;
        #pragma unroll
        for (int s = 0; s < 16; ++s) {
          int j = tid + s * T;
          if (slab[j] != mylab) continue;
          unsigned long long k = mkkey(srow[j], j);
          if (k < g && k > nb) nb = k;
        }
        h2 = nb;
      }
    }
    __syncthreads();
  }

  if (fpnum > 0 && nc > 0) {
    unsigned long long ck[KTOP];
    int cnt[KTOP];
    #pragma unroll
    for (int q = 0; q < KTOP; ++q) {
      ck[q] = (q < nc) ? candk[q] : ~0ull;
      cnt[q] = 0;
    }
    #pragma unroll
    for (int s = 0; s < 16; ++s) {
      int j = tid + s * T;
      unsigned long long k = mkkey(srow[j], j);
      #pragma unroll
      for (int q = 0; q < KTOP; ++q) cnt[q] += (k > ck[q]) ? 1 : 0;
    }
    #pragma unroll
    for (int q = 0; q < KTOP; ++q) {
      int x = cnt[q];
      #pragma unroll
      for (int off = 32; off; off >>= 1) x += __shfl_xor(x, off);
      if (lane == 0) wcnt[wid][q] = x;
    }
    __syncthreads();
    if (tid == 0) {
      float fn = 0.f;
      for (int u = 0; u < nc; ++u) {
        int rank = 1 + wcnt[0][u] + wcnt[1][u] + wcnt[2][u] + wcnt[3][u];
        int j = BB - 1 - (int)(unsigned)(candk[u] & 0xFFFFFFFFull);
        fn += srow[j] * (1.f / log2f((float)(rank + 1)) + 1.f);
      }
      partials[row] = sfp - fn;
    }
  } else if (tid == 0) {
    partials[row] = sfp;
  }
}

// ---------------- K3: deterministic final reduction ----------------
__global__ __launch_bounds__(256) void finalreduce(const float* __restrict__ partials,
                                                   float* __restrict__ out) {
  __shared__ float s[256];
  const int tid = threadIdx.x;
  float acc = 0.f;
  for (int j = tid; j < BB; j += 256) acc += partials[j];
  s[tid] = acc; __syncthreads();
  #pragma unroll
  for (int st = 128; st; st >>= 1) { if (tid < st) s[tid] += s[tid + st]; __syncthreads(); }
  if (tid == 0) out[0] = s[0];
}

extern "C" void kernel_launch(void* const* d_in, const int* in_sizes, int n_in,
                              void* d_out, int out_size, void* d_ws, size_t ws_size,
                              hipStream_t stream) {
  const float* R      = (const float*)d_in[0];
  const int*   labels = (const int*)d_in[1];
  float* out = (float*)d_out;

  float* sim            = (float*)d_ws;                                  // 64 MB
  float* sq             = (float*)((char*)d_ws + (size_t)BB * BB * 4);   // 16 KB
  float* partials       = sq + BB;                                       // 16 KB
  unsigned char* lab8   = (unsigned char*)(partials + BB);               // 4 KB

  splitbf<<<(BB * DD) / (256 * 4), 256, 0, stream>>>(R);
  sqnorm_kernel<<<BB, 64, 0, stream>>>(R, sq);
  packlab<<<BB / 256, 256, 0, stream>>>(labels, lab8);
  dim3 g(32, 32);
  simgemm_mfma<<<g, 256, 0, stream>>>(labels, sq, sim);
  rowproc2<<<BB, 256, 0, stream>>>(sim, labels, lab8, partials);
  finalreduce<<<1, 256, 0, stream>>>(partials, out);
}

// Round 4
// 149.700 us; speedup vs baseline: 3.3838x; 1.2723x over previous
//
#include <hip/hip_runtime.h>
#include <math.h>

#define BB 4096        // batch size
#define DD 512         // repr dim
#define KTOP 9         // K+1
#define MARGIN_F 0.2f

typedef __attribute__((ext_vector_type(8))) short short8;
typedef __attribute__((ext_vector_type(4))) float f32x4;
typedef unsigned long long u64;

// split-fp32 operands (4 MB each) + per-class match bitmasks (32 KB)
__device__ unsigned short g_Rhi[(size_t)BB * DD];
__device__ unsigned short g_Rlo[(size_t)BB * DD];
__device__ u64 g_cmask[64 * 64];   // [class][lane] bit e -> label[j(lane,e)]==class

// ---- bf16 helpers (RNE) ----
__device__ __forceinline__ unsigned short f2bf(float x) {
  unsigned u = __float_as_uint(x);
  u += 0x7fffu + ((u >> 16) & 1u);
  return (unsigned short)(u >> 16);
}
__device__ __forceinline__ float bf2f(unsigned short h) {
  return __uint_as_float((unsigned)h << 16);
}

__device__ __forceinline__ void gload16(void* lds, const void* g) {
  __builtin_amdgcn_global_load_lds(
      (const __attribute__((address_space(1))) void*)g,
      (__attribute__((address_space(3))) void*)lds, 16, 0, 0);
}

// ---- key: ord(val)<<32 | (4095-j)<<1 | match   (val desc, idx asc) ----
__device__ __forceinline__ float keyval(u64 k) {
  unsigned e = (unsigned)(k >> 32);
  unsigned s = (e & 0x80000000u) ? (e ^ 0x80000000u) : ~e;
  return __uint_as_float(s);
}

__device__ __forceinline__ u64 shflxor64(u64 v, int m) {
  unsigned lo = (unsigned)v, hi = (unsigned)(v >> 32);
  lo = (unsigned)__shfl_xor((int)lo, m);
  hi = (unsigned)__shfl_xor((int)hi, m);
  return ((u64)hi << 32) | lo;
}

__device__ __forceinline__ u64 wavemax64(u64 h) {
  #pragma unroll
  for (int m = 32; m; m >>= 1) {
    u64 o = shflxor64(h, m);
    if (o > h) h = o;
  }
  return h;
}

__device__ __forceinline__ float f4c(const float4& f, int q) {
  return q == 0 ? f.x : q == 1 ? f.y : q == 2 ? f.z : f.w;
}

// ---------------- K0: split R into bf16 hi/lo ----------------
__global__ __launch_bounds__(256) void splitbf(const float* __restrict__ R) {
  const int i = (blockIdx.x * 256 + threadIdx.x) * 4;
  float4 v = *(const float4*)&R[i];
  float x[4] = {v.x, v.y, v.z, v.w};
  ushort4 h, l;
  unsigned short* hp = (unsigned short*)&h;
  unsigned short* lp = (unsigned short*)&l;
  #pragma unroll
  for (int q = 0; q < 4; ++q) {
    unsigned short hh = f2bf(x[q]);
    hp[q] = hh;
    lp[q] = f2bf(x[q] - bf2f(hh));
  }
  *(ushort4*)&g_Rhi[i] = h;
  *(ushort4*)&g_Rlo[i] = l;
}

// ---------------- K0b: row squared norms (fp32, exact) ----------------
__global__ __launch_bounds__(64) void sqnorm_kernel(const float* __restrict__ R,
                                                    float* __restrict__ sq) {
  const int row = blockIdx.x;
  const int lane = threadIdx.x;
  const float* r = R + (size_t)row * DD;
  float4 v1 = ((const float4*)r)[lane];
  float4 v2 = ((const float4*)r)[lane + 64];
  float s = v1.x*v1.x + v1.y*v1.y + v1.z*v1.z + v1.w*v1.w
          + v2.x*v2.x + v2.y*v2.y + v2.z*v2.z + v2.w*v2.w;
  #pragma unroll
  for (int off = 32; off; off >>= 1) s += __shfl_down(s, off);
  if (lane == 0) sq[row] = s;
}

// ---------------- K0c: pack labels to bytes ----------------
__global__ __launch_bounds__(256) void packlab(const int* __restrict__ labels,
                                               unsigned char* __restrict__ lab8) {
  int j = blockIdx.x * 256 + threadIdx.x;
  lab8[j] = (unsigned char)labels[j];
}

// ---------------- K0d: per-class match bitmasks ----------------
// bit e of g_cmask[c][lane] corresponds to element j = 64*(e&~3) + 4*lane + (e&3)
__global__ __launch_bounds__(64) void buildmask(const unsigned char* __restrict__ lab8) {
  const int c = blockIdx.x;
  const int lane = threadIdx.x;
  u64 m = 0;
  #pragma unroll
  for (int e = 0; e < 64; ++e) {
    int j = 64 * (e & ~3) + 4 * lane + (e & 3);
    m |= (u64)(lab8[j] == (unsigned char)c) << e;
  }
  g_cmask[c * 64 + lane] = m;
}

// ---------------- K1: MFMA split-bf16 GEMM + sim epilogue (symmetric) ----------------
__global__ __launch_bounds__(256) void simgemm_mfma(const int* __restrict__ labels,
                                                    const float* __restrict__ sq,
                                                    float* __restrict__ sim) {
  const int bi = blockIdx.y, bj = blockIdx.x;
  if (bi > bj) return;
  const int i0 = bi * 128, j0 = bj * 128;

  __shared__ unsigned short smem[4 * 4096];   // Ahi | Alo | Bhi | Blo, each [128][32]
  unsigned short* sAhi = smem;
  unsigned short* sAlo = smem + 4096;
  unsigned short* sBhi = smem + 8192;
  unsigned short* sBlo = smem + 12288;

  const int tid = threadIdx.x;
  const int wid = tid >> 6, lane = tid & 63;
  const int wr = wid >> 1, wc = wid & 1;
  const int lrow = lane & 15, kblk = lane >> 4;

  f32x4 acc[4][4] = {};

  const int ch0 = wid * 2;
  const int r_a = (lane >> 2);
  const int c_a = (lane & 3) * 8;

  for (int k0 = 0; k0 < DD; k0 += 32) {
    #pragma unroll
    for (int i = 0; i < 2; ++i) {
      const int chunk = ch0 + i;
      const int r = chunk * 16 + r_a;
      const size_t ga = (size_t)(i0 + r) * DD + k0 + c_a;
      const size_t gb = (size_t)(j0 + r) * DD + k0 + c_a;
      gload16(&sAhi[chunk * 512], &g_Rhi[ga]);
      gload16(&sAlo[chunk * 512], &g_Rlo[ga]);
      gload16(&sBhi[chunk * 512], &g_Rhi[gb]);
      gload16(&sBlo[chunk * 512], &g_Rlo[gb]);
    }
    __syncthreads();

    short8 ah[4], al[4], bh[4], bl[4];
    #pragma unroll
    for (int m = 0; m < 4; ++m) {
      const int off = (wr * 64 + m * 16 + lrow) * 32 + kblk * 8;
      ah[m] = *(const short8*)&sAhi[off];
      al[m] = *(const short8*)&sAlo[off];
    }
    #pragma unroll
    for (int n = 0; n < 4; ++n) {
      const int off = (wc * 64 + n * 16 + lrow) * 32 + kblk * 8;
      bh[n] = *(const short8*)&sBhi[off];
      bl[n] = *(const short8*)&sBlo[off];
    }
    #pragma unroll
    for (int m = 0; m < 4; ++m) {
      #pragma unroll
      for (int n = 0; n < 4; ++n) {
        acc[m][n] = __builtin_amdgcn_mfma_f32_16x16x32_bf16(ah[m], bh[n], acc[m][n], 0, 0, 0);
        acc[m][n] = __builtin_amdgcn_mfma_f32_16x16x32_bf16(ah[m], bl[n], acc[m][n], 0, 0, 0);
        acc[m][n] = __builtin_amdgcn_mfma_f32_16x16x32_bf16(al[m], bh[n], acc[m][n], 0, 0, 0);
      }
    }
    __syncthreads();
  }

  float* sqi = (float*)smem;
  float* sqj = sqi + 128;
  int* labi = (int*)(sqj + 128);
  int* labj = labi + 128;
  if (tid < 128) { sqi[tid] = sq[i0 + tid]; labi[tid] = labels[i0 + tid]; }
  else { int t = tid - 128; sqj[t] = sq[j0 + t]; labj[t] = labels[j0 + t]; }
  __syncthreads();

  const bool offdiag = (bi != bj);
  #pragma unroll
  for (int m = 0; m < 4; ++m) {
    const int rbase = wr * 64 + m * 16 + kblk * 4;
    #pragma unroll
    for (int n = 0; n < 4; ++n) {
      const int ccol = wc * 64 + n * 16 + lrow;
      const float sqc = sqj[ccol];
      const int lc_ = labj[ccol];
      float4 vals;
      float* vp = (float*)&vals;
      #pragma unroll
      for (int reg = 0; reg < 4; ++reg) {
        const int r = rbase + reg;
        float res = sqi[r] - 2.0f * acc[m][n][reg] + sqc;
        float dd = (res <= 0.f) ? 0.f : sqrtf(res);
        float sv = -dd + ((labi[r] != lc_) ? MARGIN_F : 0.f);
        vp[reg] = sv;
        sim[(size_t)(i0 + r) * BB + (j0 + ccol)] = sv;
      }
      if (offdiag) {
        *(float4*)&sim[(size_t)(j0 + ccol) * BB + (i0 + rbase)] = vals;
      }
    }
  }
}

// ---------------- K2: wave-per-row rank processing, register-resident ----------------
// Element e (0..63) of lane: j = 64*(e&~3) + 4*lane + (e&3).
// key = ord<<32 | (4095-j)<<1 | match.
#define EKEY(e) ({                                                             \
  float _val = f4c(v[(e) >> 2], (e) & 3);                                      \
  unsigned _su = __float_as_uint(_val);                                        \
  unsigned _ord = _su ^ ((unsigned)((int)_su >> 31) | 0x80000000u);            \
  unsigned _lo = lowbase - (unsigned)((64 * ((e) & ~3) + ((e) & 3)) << 1)      \
               + (unsigned)((mask >> (e)) & 1ull);                             \
  ((u64)_ord << 32) | _lo; })

#define TOP2UPD(k, a, b) {                                                     \
  u64 _mx = ((k) > (a)) ? (k) : (a);                                           \
  u64 _mn = ((k) > (a)) ? (a) : (k);                                           \
  (a) = _mx;                                                                   \
  (b) = (_mn > (b)) ? _mn : (b); }

__global__ __launch_bounds__(256) void rowproc3(const float* __restrict__ sim,
                                                const unsigned char* __restrict__ lab8,
                                                float* __restrict__ partials) {
  const int tid = threadIdx.x;
  const int lane = tid & 63;
  const int row = blockIdx.x * 4 + (tid >> 6);

  const float4* rowp = (const float4*)(sim + (size_t)row * BB);
  float4 v[16];
  #pragma unroll
  for (int s = 0; s < 16; ++s) v[s] = rowp[lane + s * 64];

  const int myl = lab8[row];
  const u64 mask = g_cmask[myl * 64 + lane];
  const unsigned lowbase = 8190u - 8u * (unsigned)lane;

  // ---- per-lane top-2 + pos count ----
  u64 h1 = 0, h2 = 0;
  #pragma unroll
  for (int e = 0; e < 64; ++e) {
    u64 k = EKEY(e);
    TOP2UPD(k, h1, h2);
  }
  int pos = __popcll(mask);
  #pragma unroll
  for (int m = 32; m; m >>= 1) pos += __shfl_xor(pos, m);
  const int ks = min(pos, KTOP);

  // ---- top-ks pops (lazy top-2; rescan only on 3rd+ win per lane) ----
  u64 kth = 0;
  float fp = 0.f; int fpn = 0;
  #pragma unroll
  for (int t = 0; t < KTOP; ++t) {
    if (t < ks) {
      u64 g = wavemax64(h1);
      if (!(g & 1ull)) { fp += keyval(g) * (1.f / log2f((float)(t + 2)) + 1.f); fpn++; }
      if (t == ks - 1) kth = g;
      if (h1 == g) {
        h1 = h2; h2 = ~0ull;
        if (h1 == ~0ull) {
          h1 = 0; h2 = 0;
          #pragma unroll
          for (int e = 0; e < 64; ++e) {
            u64 k = EKEY(e);
            if (k < g) TOP2UPD(k, h1, h2);
          }
        }
      }
    }
  }

  // ---- fn: top-fpn same-class keys below kth, weighted by true global rank ----
  float fn = 0.f;
  if (fpn > 0) {
    u64 f1 = 0, f2 = 0;
    #pragma unroll
    for (int e = 0; e < 64; ++e) {
      u64 k = EKEY(e);
      if ((k & 1ull) && k < kth) TOP2UPD(k, f1, f2);
    }
    u64 ck[KTOP];
    int nc = 0;
    #pragma unroll
    for (int u = 0; u < KTOP; ++u) {
      ck[u] = ~0ull;
      if (u < fpn) {
        u64 g = wavemax64(f1);
        if (g != 0ull) {
          ck[u] = g; nc = u + 1;
          if (f1 == g) {
            f1 = f2; f2 = ~0ull;
            if (f1 == ~0ull) {
              f1 = 0; f2 = 0;
              #pragma unroll
              for (int e = 0; e < 64; ++e) {
                u64 k = EKEY(e);
                if ((k & 1ull) && k < g) TOP2UPD(k, f1, f2);
              }
            }
          }
        }
      }
    }
    if (nc > 0) {
      int cnt[KTOP];
      #pragma unroll
      for (int u = 0; u < KTOP; ++u) cnt[u] = 0;
      #pragma unroll
      for (int e = 0; e < 64; ++e) {
        u64 k = EKEY(e);
        #pragma unroll
        for (int u = 0; u < KTOP; ++u) cnt[u] += (k > ck[u]) ? 1 : 0;
      }
      #pragma unroll
      for (int u = 0; u < KTOP; ++u) {
        #pragma unroll
        for (int m = 32; m; m >>= 1) cnt[u] += __shfl_xor(cnt[u], m);
      }
      #pragma unroll
      for (int u = 0; u < KTOP; ++u) {
        if (u < nc) {
          int rank = 1 + cnt[u];
          fn += keyval(ck[u]) * (1.f / log2f((float)(rank + 1)) + 1.f);
        }
      }
    }
  }

  if (lane == 0) partials[row] = fp - fn;
}

// ---------------- K3: deterministic final reduction ----------------
__global__ __launch_bounds__(256) void finalreduce(const float* __restrict__ partials,
                                                   float* __restrict__ out) {
  __shared__ float s[256];
  const int tid = threadIdx.x;
  float acc = 0.f;
  for (int j = tid; j < BB; j += 256) acc += partials[j];
  s[tid] = acc; __syncthreads();
  #pragma unroll
  for (int st = 128; st; st >>= 1) { if (tid < st) s[tid] += s[tid + st]; __syncthreads(); }
  if (tid == 0) out[0] = s[0];
}

extern "C" void kernel_launch(void* const* d_in, const int* in_sizes, int n_in,
                              void* d_out, int out_size, void* d_ws, size_t ws_size,
                              hipStream_t stream) {
  const float* R      = (const float*)d_in[0];
  const int*   labels = (const int*)d_in[1];
  float* out = (float*)d_out;

  float* sim            = (float*)d_ws;                                  // 64 MB
  float* sq             = (float*)((char*)d_ws + (size_t)BB * BB * 4);   // 16 KB
  float* partials       = sq + BB;                                       // 16 KB
  unsigned char* lab8   = (unsigned char*)(partials + BB);               // 4 KB

  splitbf<<<(BB * DD) / (256 * 4), 256, 0, stream>>>(R);
  sqnorm_kernel<<<BB, 64, 0, stream>>>(R, sq);
  packlab<<<BB / 256, 256, 0, stream>>>(labels, lab8);
  buildmask<<<64, 64, 0, stream>>>(lab8);
  dim3 g(32, 32);
  simgemm_mfma<<<g, 256, 0, stream>>>(labels, sq, sim);
  rowproc3<<<BB / 4, 256, 0, stream>>>(sim, lab8, partials);
  finalreduce<<<1, 256, 0, stream>>>(partials, out);
}

// Round 5
// 134.187 us; speedup vs baseline: 3.7750x; 1.1156x over previous
//
#include <hip/hip_runtime.h>
#include <math.h>

#define BB 4096        // batch size
#define DD 512         // repr dim
#define KTOP 9         // K+1
#define MARGIN_F 0.2f
#define NTILE 32       // 4096/128
#define NTRI (NTILE * (NTILE + 1) / 2)   // 528 upper-triangle blocks

typedef __attribute__((ext_vector_type(8))) short short8;
typedef __attribute__((ext_vector_type(4))) float f32x4;
typedef unsigned long long u64;

// split-fp32 operands (4 MB each) + per-class match bitmasks (32 KB)
__device__ unsigned short g_Rhi[(size_t)BB * DD];
__device__ unsigned short g_Rlo[(size_t)BB * DD];
__device__ u64 g_cmask[64 * 64];   // [class][lane] bit e -> label[j(lane,e)]==class

// ---- bf16 helpers (RNE) ----
__device__ __forceinline__ unsigned short f2bf(float x) {
  unsigned u = __float_as_uint(x);
  u += 0x7fffu + ((u >> 16) & 1u);
  return (unsigned short)(u >> 16);
}
__device__ __forceinline__ float bf2f(unsigned short h) {
  return __uint_as_float((unsigned)h << 16);
}

__device__ __forceinline__ void gload16(void* lds, const void* g) {
  __builtin_amdgcn_global_load_lds(
      (const __attribute__((address_space(1))) void*)g,
      (__attribute__((address_space(3))) void*)lds, 16, 0, 0);
}

// ---- key: ord(val)<<32 | (4095-j)<<1 | match   (val desc, idx asc) ----
__device__ __forceinline__ float keyval(u64 k) {
  unsigned e = (unsigned)(k >> 32);
  unsigned s = (e & 0x80000000u) ? (e ^ 0x80000000u) : ~e;
  return __uint_as_float(s);
}

__device__ __forceinline__ u64 shflxor64(u64 v, int m) {
  unsigned lo = (unsigned)v, hi = (unsigned)(v >> 32);
  lo = (unsigned)__shfl_xor((int)lo, m);
  hi = (unsigned)__shfl_xor((int)hi, m);
  return ((u64)hi << 32) | lo;
}

__device__ __forceinline__ u64 wavemax64(u64 h) {
  #pragma unroll
  for (int m = 32; m; m >>= 1) {
    u64 o = shflxor64(h, m);
    if (o > h) h = o;
  }
  return h;
}

__device__ __forceinline__ float f4c(const float4& f, int q) {
  return q == 0 ? f.x : q == 1 ? f.y : q == 2 ? f.z : f.w;
}

// ---------------- K0: split R into bf16 hi/lo ----------------
__global__ __launch_bounds__(256) void splitbf(const float* __restrict__ R) {
  const int i = (blockIdx.x * 256 + threadIdx.x) * 4;
  float4 v = *(const float4*)&R[i];
  float x[4] = {v.x, v.y, v.z, v.w};
  ushort4 h, l;
  unsigned short* hp = (unsigned short*)&h;
  unsigned short* lp = (unsigned short*)&l;
  #pragma unroll
  for (int q = 0; q < 4; ++q) {
    unsigned short hh = f2bf(x[q]);
    hp[q] = hh;
    lp[q] = f2bf(x[q] - bf2f(hh));
  }
  *(ushort4*)&g_Rhi[i] = h;
  *(ushort4*)&g_Rlo[i] = l;
}

// ---------------- K0b: row squared norms (fp32, exact) ----------------
__global__ __launch_bounds__(64) void sqnorm_kernel(const float* __restrict__ R,
                                                    float* __restrict__ sq) {
  const int row = blockIdx.x;
  const int lane = threadIdx.x;
  const float* r = R + (size_t)row * DD;
  float4 v1 = ((const float4*)r)[lane];
  float4 v2 = ((const float4*)r)[lane + 64];
  float s = v1.x*v1.x + v1.y*v1.y + v1.z*v1.z + v1.w*v1.w
          + v2.x*v2.x + v2.y*v2.y + v2.z*v2.z + v2.w*v2.w;
  #pragma unroll
  for (int off = 32; off; off >>= 1) s += __shfl_down(s, off);
  if (lane == 0) sq[row] = s;
}

// ---------------- K0c: pack labels to bytes ----------------
__global__ __launch_bounds__(256) void packlab(const int* __restrict__ labels,
                                               unsigned char* __restrict__ lab8) {
  int j = blockIdx.x * 256 + threadIdx.x;
  lab8[j] = (unsigned char)labels[j];
}

// ---------------- K0d: per-class match bitmasks ----------------
__global__ __launch_bounds__(64) void buildmask(const unsigned char* __restrict__ lab8) {
  const int c = blockIdx.x;
  const int lane = threadIdx.x;
  u64 m = 0;
  #pragma unroll
  for (int e = 0; e < 64; ++e) {
    int j = 64 * (e & ~3) + 4 * lane + (e & 3);
    m |= (u64)(lab8[j] == (unsigned char)c) << e;
  }
  g_cmask[c * 64 + lane] = m;
}

// ---------------- K1: MFMA split-bf16 GEMM, compact tri grid, 2-phase dbuf ----------------
// LDS slot swizzle: LDS[r][s] holds global column-group s^(r&3); dest stays linear
// (gload_lds requirement), the permutation rides on the GLOBAL source address, and
// ds_read applies the same XOR. Quarter-wave reads spread over 8 bank-quads (2-way, free).
__global__ __launch_bounds__(256) void simgemm_mfma(const int* __restrict__ labels,
                                                    const float* __restrict__ sq,
                                                    float* __restrict__ sim) {
  int tt = blockIdx.x, bi = 0, rem = NTILE;
  while (tt >= rem) { tt -= rem; --rem; ++bi; }
  const int bj = bi + tt;
  const int i0 = bi * 128, j0 = bj * 128;

  __shared__ unsigned short smem[2][4 * 4096];   // 2 x (Ahi|Alo|Bhi|Blo @ [128][32])

  const int tid = threadIdx.x;
  const int wid = tid >> 6, lane = tid & 63;
  const int wr = wid >> 1, wc = wid & 1;
  const int lrow = lane & 15, kblk = lane >> 4;

  const int ch0 = wid * 2;
  const int r_a = lane >> 2;
  const int c_sw = (((lane & 3) ^ ((lane >> 2) & 3)) * 8);  // pre-swizzled source col

  f32x4 acc[4][4] = {};

  auto stage = [&](unsigned short* buf, int k0) {
    unsigned short* sAhi = buf;
    unsigned short* sAlo = buf + 4096;
    unsigned short* sBhi = buf + 8192;
    unsigned short* sBlo = buf + 12288;
    #pragma unroll
    for (int i = 0; i < 2; ++i) {
      const int chunk = ch0 + i;
      const int r = chunk * 16 + r_a;
      const size_t ga = (size_t)(i0 + r) * DD + k0 + c_sw;
      const size_t gb = (size_t)(j0 + r) * DD + k0 + c_sw;
      gload16(&sAhi[chunk * 512], &g_Rhi[ga]);
      gload16(&sAlo[chunk * 512], &g_Rlo[ga]);
      gload16(&sBhi[chunk * 512], &g_Rhi[gb]);
      gload16(&sBlo[chunk * 512], &g_Rlo[gb]);
    }
  };

  stage(smem[0], 0);   // prologue prefetch

  for (int step = 0; step < 16; ++step) {
    const int cur = step & 1;
    __syncthreads();   // drains vmcnt: stage(cur) landed; prev reads of cur^1 done
    if (step < 15) stage(smem[cur ^ 1], (step + 1) * 32);   // loads fly under MFMA

    unsigned short* sAhi = smem[cur];
    unsigned short* sAlo = smem[cur] + 4096;
    unsigned short* sBhi = smem[cur] + 8192;
    unsigned short* sBlo = smem[cur] + 12288;

    short8 ah[4], al[4], bh[4], bl[4];
    #pragma unroll
    for (int m = 0; m < 4; ++m) {
      const int rr = wr * 64 + m * 16 + lrow;
      const int off = rr * 32 + ((kblk ^ (lrow & 3)) * 8);
      ah[m] = *(const short8*)&sAhi[off];
      al[m] = *(const short8*)&sAlo[off];
    }
    #pragma unroll
    for (int n = 0; n < 4; ++n) {
      const int rr = wc * 64 + n * 16 + lrow;
      const int off = rr * 32 + ((kblk ^ (lrow & 3)) * 8);
      bh[n] = *(const short8*)&sBhi[off];
      bl[n] = *(const short8*)&sBlo[off];
    }
    #pragma unroll
    for (int m = 0; m < 4; ++m) {
      #pragma unroll
      for (int n = 0; n < 4; ++n) {
        acc[m][n] = __builtin_amdgcn_mfma_f32_16x16x32_bf16(ah[m], bh[n], acc[m][n], 0, 0, 0);
        acc[m][n] = __builtin_amdgcn_mfma_f32_16x16x32_bf16(ah[m], bl[n], acc[m][n], 0, 0, 0);
        acc[m][n] = __builtin_amdgcn_mfma_f32_16x16x32_bf16(al[m], bh[n], acc[m][n], 0, 0, 0);
      }
    }
  }

  __syncthreads();
  float* sqi = (float*)smem;
  float* sqj = sqi + 128;
  int* labi = (int*)(sqj + 128);
  int* labj = labi + 128;
  if (tid < 128) { sqi[tid] = sq[i0 + tid]; labi[tid] = labels[i0 + tid]; }
  else { int t2 = tid - 128; sqj[t2] = sq[j0 + t2]; labj[t2] = labels[j0 + t2]; }
  __syncthreads();

  const bool offdiag = (bi != bj);
  #pragma unroll
  for (int m = 0; m < 4; ++m) {
    const int rbase = wr * 64 + m * 16 + kblk * 4;
    #pragma unroll
    for (int n = 0; n < 4; ++n) {
      const int ccol = wc * 64 + n * 16 + lrow;
      const float sqc = sqj[ccol];
      const int lc_ = labj[ccol];
      float4 vals;
      float* vp = (float*)&vals;
      #pragma unroll
      for (int reg = 0; reg < 4; ++reg) {
        const int r = rbase + reg;
        float res = sqi[r] - 2.0f * acc[m][n][reg] + sqc;
        float dd = (res <= 0.f) ? 0.f : sqrtf(res);
        float sv = -dd + ((labi[r] != lc_) ? MARGIN_F : 0.f);
        vp[reg] = sv;
        sim[(size_t)(i0 + r) * BB + (j0 + ccol)] = sv;
      }
      if (offdiag) {
        *(float4*)&sim[(size_t)(j0 + ccol) * BB + (i0 + rbase)] = vals;
      }
    }
  }
}

// ---------------- K2: wave-per-row rank processing (1 wave / block) ----------------
#define EKEY(e) ({                                                             \
  float _val = f4c(v[(e) >> 2], (e) & 3);                                      \
  unsigned _su = __float_as_uint(_val);                                        \
  unsigned _ord = _su ^ ((unsigned)((int)_su >> 31) | 0x80000000u);            \
  unsigned _lo = lowbase - (unsigned)((64 * ((e) & ~3) + ((e) & 3)) << 1)      \
               + (unsigned)((mask >> (e)) & 1ull);                             \
  ((u64)_ord << 32) | _lo; })

#define TOP2UPD(k, a, b) {                                                     \
  u64 _mx = ((k) > (a)) ? (k) : (a);                                           \
  u64 _mn = ((k) > (a)) ? (a) : (k);                                           \
  (a) = _mx;                                                                   \
  (b) = (_mn > (b)) ? _mn : (b); }

__global__ __launch_bounds__(64) void rowproc3(const float* __restrict__ sim,
                                               const unsigned char* __restrict__ lab8,
                                               float* __restrict__ partials) {
  const int lane = threadIdx.x;
  const int row = blockIdx.x;

  const float4* rowp = (const float4*)(sim + (size_t)row * BB);
  float4 v[16];
  #pragma unroll
  for (int s = 0; s < 16; ++s) v[s] = rowp[lane + s * 64];

  const int myl = lab8[row];
  const u64 mask = g_cmask[myl * 64 + lane];
  const unsigned lowbase = 8190u - 8u * (unsigned)lane;

  u64 h1 = 0, h2 = 0;
  #pragma unroll
  for (int e = 0; e < 64; ++e) {
    u64 k = EKEY(e);
    TOP2UPD(k, h1, h2);
  }
  int pos = __popcll(mask);
  #pragma unroll
  for (int m = 32; m; m >>= 1) pos += __shfl_xor(pos, m);
  const int ks = min(pos, KTOP);

  u64 kth = 0;
  float fp = 0.f; int fpn = 0;
  #pragma unroll
  for (int t = 0; t < KTOP; ++t) {
    if (t < ks) {
      u64 g = wavemax64(h1);
      if (!(g & 1ull)) { fp += keyval(g) * (1.f / log2f((float)(t + 2)) + 1.f); fpn++; }
      if (t == ks - 1) kth = g;
      if (h1 == g) {
        h1 = h2; h2 = ~0ull;
        if (h1 == ~0ull) {
          h1 = 0; h2 = 0;
          #pragma unroll
          for (int e = 0; e < 64; ++e) {
            u64 k = EKEY(e);
            if (k < g) TOP2UPD(k, h1, h2);
          }
        }
      }
    }
  }

  float fn = 0.f;
  if (fpn > 0) {
    u64 f1 = 0, f2 = 0;
    #pragma unroll
    for (int e = 0; e < 64; ++e) {
      u64 k = EKEY(e);
      if ((k & 1ull) && k < kth) TOP2UPD(k, f1, f2);
    }
    u64 ck[KTOP];
    int nc = 0;
    #pragma unroll
    for (int u = 0; u < KTOP; ++u) {
      ck[u] = ~0ull;
      if (u < fpn) {
        u64 g = wavemax64(f1);
        if (g != 0ull) {
          ck[u] = g; nc = u + 1;
          if (f1 == g) {
            f1 = f2; f2 = ~0ull;
            if (f1 == ~0ull) {
              f1 = 0; f2 = 0;
              #pragma unroll
              for (int e = 0; e < 64; ++e) {
                u64 k = EKEY(e);
                if ((k & 1ull) && k < g) TOP2UPD(k, f1, f2);
              }
            }
          }
        }
      }
    }
    if (nc > 0) {
      int cnt[KTOP];
      #pragma unroll
      for (int u = 0; u < KTOP; ++u) cnt[u] = 0;
      #pragma unroll
      for (int e = 0; e < 64; ++e) {
        u64 k = EKEY(e);
        #pragma unroll
        for (int u = 0; u < KTOP; ++u) cnt[u] += (k > ck[u]) ? 1 : 0;
      }
      #pragma unroll
      for (int u = 0; u < KTOP; ++u) {
        #pragma unroll
        for (int m = 32; m; m >>= 1) cnt[u] += __shfl_xor(cnt[u], m);
      }
      #pragma unroll
      for (int u = 0; u < KTOP; ++u) {
        if (u < nc) {
          int rank = 1 + cnt[u];
          fn += keyval(ck[u]) * (1.f / log2f((float)(rank + 1)) + 1.f);
        }
      }
    }
  }

  if (lane == 0) partials[row] = fp - fn;
}

// ---------------- K3: deterministic final reduction ----------------
__global__ __launch_bounds__(256) void finalreduce(const float* __restrict__ partials,
                                                   float* __restrict__ out) {
  __shared__ float s[256];
  const int tid = threadIdx.x;
  float acc = 0.f;
  for (int j = tid; j < BB; j += 256) acc += partials[j];
  s[tid] = acc; __syncthreads();
  #pragma unroll
  for (int st = 128; st; st >>= 1) { if (tid < st) s[tid] += s[tid + st]; __syncthreads(); }
  if (tid == 0) out[0] = s[0];
}

extern "C" void kernel_launch(void* const* d_in, const int* in_sizes, int n_in,
                              void* d_out, int out_size, void* d_ws, size_t ws_size,
                              hipStream_t stream) {
  const float* R      = (const float*)d_in[0];
  const int*   labels = (const int*)d_in[1];
  float* out = (float*)d_out;

  float* sim            = (float*)d_ws;                                  // 64 MB
  float* sq             = (float*)((char*)d_ws + (size_t)BB * BB * 4);   // 16 KB
  float* partials       = sq + BB;                                       // 16 KB
  unsigned char* lab8   = (unsigned char*)(partials + BB);               // 4 KB

  splitbf<<<(BB * DD) / (256 * 4), 256, 0, stream>>>(R);
  sqnorm_kernel<<<BB, 64, 0, stream>>>(R, sq);
  packlab<<<BB / 256, 256, 0, stream>>>(labels, lab8);
  buildmask<<<64, 64, 0, stream>>>(lab8);
  simgemm_mfma<<<NTRI, 256, 0, stream>>>(labels, sq, sim);
  rowproc3<<<BB, 64, 0, stream>>>(sim, lab8, partials);
  finalreduce<<<1, 256, 0, stream>>>(partials, out);
}